// Round 26
// baseline (51.228 us; speedup 1.0000x reference)
//
#include <hip/hip_runtime.h>
#include <hip/hip_bf16.h>
#include <math.h>

#define TT 512
#define CC 1024
#define NH 16
#define NKV 8
#define HD 64
static constexpr float EPS_ = 1e-6f;

typedef short bf16x8 __attribute__((ext_vector_type(8)));
typedef float f32x4 __attribute__((ext_vector_type(4)));
typedef _Float16 half2v __attribute__((ext_vector_type(2)));

__device__ __forceinline__ ushort f2bf(float f) {
  union { __hip_bfloat16 h; ushort u; } cv;
  cv.h = __float2bfloat16(f);
  return cv.u;
}
__device__ __forceinline__ ushort f2h(float f) {
  union { _Float16 h; ushort u; } cv;
  cv.h = (_Float16)f;
  return cv.u;
}
__device__ __forceinline__ half2v bch2(uint u) {
  union { uint u; half2v h; } cv;
  cv.u = u;
  return cv.h;
}

// no-op probe kernel (1 block x 64 thr): measures pure launch overhead
__global__ void noop_kernel() {}

// ---------------------------------------------------------------------------
// prep: x -> bf16 (same layout); Wq/Wk/Wv/Wo -> transposed bf16 Wt[n][k]
// ---------------------------------------------------------------------------
__global__ __launch_bounds__(256) void prep_kernel(
    const float* __restrict__ x,
    const float* __restrict__ Wq, const float* __restrict__ Wk,
    const float* __restrict__ Wv, const float* __restrict__ Wo,
    ushort* __restrict__ xb, ushort* __restrict__ Wtq, ushort* __restrict__ Wtk,
    ushort* __restrict__ Wtv, ushort* __restrict__ Wto)
{
  int b = blockIdx.x;
  if (b < 256) {
    int base = b * 2048 + threadIdx.x * 8;
    float4 f0 = *reinterpret_cast<const float4*>(&x[base]);
    float4 f1 = *reinterpret_cast<const float4*>(&x[base + 4]);
    union { ushort u[8]; uint4 v; } pk;
    pk.u[0] = f2bf(f0.x); pk.u[1] = f2bf(f0.y); pk.u[2] = f2bf(f0.z); pk.u[3] = f2bf(f0.w);
    pk.u[4] = f2bf(f1.x); pk.u[5] = f2bf(f1.y); pk.u[6] = f2bf(f1.z); pk.u[7] = f2bf(f1.w);
    *reinterpret_cast<uint4*>(&xb[base]) = pk.v;
    return;
  }
  b -= 256;
  const float* W; ushort* Wt; int ldW, tr, tc;
  if (b < 256)      { W = Wq; Wt = Wtq; ldW = 1024; tr = b >> 4;       tc = b & 15; }
  else if (b < 384) { int q = b - 256; W = Wk; Wt = Wtk; ldW = 512; tr = q >> 3; tc = q & 7; }
  else if (b < 512) { int q = b - 384; W = Wv; Wt = Wtv; ldW = 512; tr = q >> 3; tc = q & 7; }
  else              { int q = b - 512; W = Wo; Wt = Wto; ldW = 1024; tr = q >> 4; tc = q & 15; }
  const int k0 = tr * 64, n0 = tc * 64;
  __shared__ float ft[64][65];
  const int t = threadIdx.x;
#pragma unroll
  for (int it = 0; it < 4; ++it) {
    int q = t + it * 256;
    int r = q >> 4, c4 = q & 15;
    float4 f = *reinterpret_cast<const float4*>(&W[(k0 + r) * ldW + n0 + c4 * 4]);
    ft[r][c4 * 4 + 0] = f.x; ft[r][c4 * 4 + 1] = f.y;
    ft[r][c4 * 4 + 2] = f.z; ft[r][c4 * 4 + 3] = f.w;
  }
  __syncthreads();
#pragma unroll
  for (int it = 0; it < 2; ++it) {
    int q = t + it * 256;
    int n = q >> 3, kc = q & 7;
    union { ushort u[8]; uint4 v; } pk;
#pragma unroll
    for (int j = 0; j < 8; ++j) pk.u[j] = f2bf(ft[kc * 8 + j][n]);
    *reinterpret_cast<uint4*>(&Wt[(n0 + n) * 1024 + k0 + kc * 8]) = pk.v;
  }
}

// ---------------------------------------------------------------------------
// Fused QKV GEMM + rope/rms/pack epilogue (R23-proven). 32x64 tiles,
// grid (32,16) = 512 blocks, BK=128.
// ---------------------------------------------------------------------------
__global__ __launch_bounds__(256) void qkv_rope_kernel(
    const ushort* __restrict__ xb,
    const ushort* __restrict__ Wtq, const ushort* __restrict__ Wtk, const ushort* __restrict__ Wtv,
    const float* __restrict__ cosb, const float* __restrict__ sinb,
    uint* __restrict__ qh, uint* __restrict__ kth, ushort* __restrict__ vt)
{
  __shared__ ushort At[32][136];
  __shared__ ushort Bs[64][136];
  __shared__ float ft[32][65];
  const int tid = threadIdx.x;
  const int lane = tid & 63, w = tid >> 6;
  const int bx = blockIdx.x, by = blockIdx.y;
  const int row0 = by * 32;

  const ushort* Bt; int col0;
  if (bx < 16)      { Bt = Wtq; col0 = bx * 64; }
  else if (bx < 24) { Bt = Wtk; col0 = (bx - 16) * 64; }
  else              { Bt = Wtv; col0 = (bx - 24) * 64; }

  const int m0 = (w & 1) * 16, n0 = (w >> 1) * 32;
  const int lr = lane & 15, lk = (lane >> 4) * 8;
  f32x4 acc[2] = {};
  const int srA = tid >> 3, scA = (tid & 7) * 16;
  const int srB = tid >> 2, scB = (tid & 3) * 32;
  const ushort* Ap = &xb[(row0 + srA) * 1024 + scA];
  const ushort* Bp = &Bt[(col0 + srB) * 1024 + scB];

  for (int k0 = 0; k0 < 1024; k0 += 128) {
    __syncthreads();
    uint4 a0 = *reinterpret_cast<const uint4*>(Ap + k0);
    uint4 a1 = *reinterpret_cast<const uint4*>(Ap + k0 + 8);
    uint4 b0 = *reinterpret_cast<const uint4*>(Bp + k0);
    uint4 b1 = *reinterpret_cast<const uint4*>(Bp + k0 + 8);
    uint4 b2 = *reinterpret_cast<const uint4*>(Bp + k0 + 16);
    uint4 b3 = *reinterpret_cast<const uint4*>(Bp + k0 + 24);
    *reinterpret_cast<uint4*>(&At[srA][scA]) = a0;
    *reinterpret_cast<uint4*>(&At[srA][scA + 8]) = a1;
    *reinterpret_cast<uint4*>(&Bs[srB][scB]) = b0;
    *reinterpret_cast<uint4*>(&Bs[srB][scB + 8]) = b1;
    *reinterpret_cast<uint4*>(&Bs[srB][scB + 16]) = b2;
    *reinterpret_cast<uint4*>(&Bs[srB][scB + 24]) = b3;
    __syncthreads();
#pragma unroll
    for (int kk = 0; kk < 4; ++kk) {
      bf16x8 af = *reinterpret_cast<const bf16x8*>(&At[m0 + lr][kk * 32 + lk]);
#pragma unroll
      for (int ni = 0; ni < 2; ++ni) {
        bf16x8 bg = *reinterpret_cast<const bf16x8*>(&Bs[n0 + ni * 16 + lr][kk * 32 + lk]);
        acc[ni] = __builtin_amdgcn_mfma_f32_16x16x32_bf16(af, bg, acc[ni], 0, 0, 0);
      }
    }
  }

  const int crow = (lane >> 4) * 4, ccol = lane & 15;
  __syncthreads();
#pragma unroll
  for (int ni = 0; ni < 2; ++ni)
#pragma unroll
    for (int r = 0; r < 4; ++r)
      ft[m0 + crow + r][n0 + ni * 16 + ccol] = acc[ni][r];
  __syncthreads();

  if (bx < 16) {                         // q: rope+rms -> packed half2 qh
    const int h = bx;
#pragma unroll 2
    for (int rr = 0; rr < 8; ++rr) {
      int row = w * 8 + rr;
      int t = row0 + row;
      float vv = ft[row][lane];
      float pt = ft[row][lane ^ 32];
      int f = lane & 31;
      float c = cosb[t * 32 + f], s = sinb[t * 32 + f];
      float o = (lane < 32) ? (vv * c - pt * s) : (pt * s + vv * c);
      float ss = o * o;
#pragma unroll
      for (int off = 32; off; off >>= 1) ss += __shfl_xor(ss, off);
      float rN = rsqrtf(ss * (1.0f / 64.0f) + EPS_);
      uint hv = (uint)f2h(o * rN);
      uint nb = __shfl_down(hv, 1);
      if ((lane & 1) == 0)
        qh[(t * 16 + h) * 32 + (lane >> 1)] = hv | (nb << 16);
    }
    return;
  }
  if (bx < 24) {                         // k: rope+rms -> packed half2 K^T
    const int g = bx - 16;
#pragma unroll 2
    for (int rr = 0; rr < 8; ++rr) {
      int row = w * 8 + rr;
      int t = row0 + row;
      float vv = ft[row][lane];
      float pt = ft[row][lane ^ 32];
      int f = lane & 31;
      float c = cosb[t * 32 + f], s = sinb[t * 32 + f];
      float o = (lane < 32) ? (vv * c - pt * s) : (pt * s + vv * c);
      float ss = o * o;
#pragma unroll
      for (int off = 32; off; off >>= 1) ss += __shfl_xor(ss, off);
      ft[row][lane] = o * rsqrtf(ss * (1.0f / 64.0f) + EPS_);
    }
    __syncthreads();
#pragma unroll
    for (int it = 0; it < 4; ++it) {
      int idx2 = tid + it * 256;
      int d2 = idx2 >> 5, tt = idx2 & 31;
      uint lo = (uint)f2h(ft[tt][2 * d2]);
      uint hi = (uint)f2h(ft[tt][2 * d2 + 1]);
      kth[g * 16384 + d2 * 512 + row0 + tt] = lo | (hi << 16);
    }
    return;
  }
  // v: convert + transpose -> vt (bf16)
  const int g = bx - 24;
#pragma unroll
  for (int it = 0; it < 4; ++it) {
    int idx2 = tid + it * 256;
    int d = idx2 >> 4, tp = idx2 & 15;
    uint o = (uint)f2bf(ft[tp * 2][d]) | ((uint)f2bf(ft[tp * 2 + 1][d]) << 16);
    *reinterpret_cast<uint*>(&vt[g * 32768 + d * 512 + row0 + tp * 2]) = o;
  }
}

// ---------------------------------------------------------------------------
// out GEMM, 16x64 tiles: grid (16,32) = 512 blocks (R23-proven).
// ---------------------------------------------------------------------------
__global__ __launch_bounds__(256) void out_mfma16_kernel(
    const ushort* __restrict__ yb, const ushort* __restrict__ Wto, float* __restrict__ out)
{
  __shared__ ushort At[16][72];
  __shared__ ushort Bs[64][72];
  const int tid = threadIdx.x;
  const int lane = tid & 63, w = tid >> 6;
  const int row0 = blockIdx.y * 16, col0 = blockIdx.x * 64;
  const int lr = lane & 15, lk = (lane >> 4) * 8;
  f32x4 acc = {};
  const int srA = tid >> 4, scA = (tid & 15) * 4;
  const int srB = tid >> 2, scB = (tid & 3) * 16;
  const ushort* Ap = &yb[(row0 + srA) * 1024 + scA];
  const ushort* Bp = &Wto[(col0 + srB) * 1024 + scB];

  for (int k0 = 0; k0 < 1024; k0 += 64) {
    __syncthreads();
    uint2 a0 = *reinterpret_cast<const uint2*>(Ap + k0);
    uint4 b0 = *reinterpret_cast<const uint4*>(Bp + k0);
    uint4 b1 = *reinterpret_cast<const uint4*>(Bp + k0 + 8);
    *reinterpret_cast<uint2*>(&At[srA][scA]) = a0;
    *reinterpret_cast<uint4*>(&Bs[srB][scB]) = b0;
    *reinterpret_cast<uint4*>(&Bs[srB][scB + 8]) = b1;
    __syncthreads();
#pragma unroll
    for (int kk = 0; kk < 2; ++kk) {
      bf16x8 af = *reinterpret_cast<const bf16x8*>(&At[lr][kk * 32 + lk]);
      bf16x8 bg = *reinterpret_cast<const bf16x8*>(&Bs[w * 16 + lr][kk * 32 + lk]);
      acc = __builtin_amdgcn_mfma_f32_16x16x32_bf16(af, bg, acc, 0, 0, 0);
    }
  }
  const int crow = (lane >> 4) * 4, ccol = lane & 15;
#pragma unroll
  for (int r = 0; r < 4; ++r)
    out[(row0 + crow + r) * 1024 + col0 + w * 16 + ccol] = acc[r];
}

// ---------------------------------------------------------------------------
// Fused attention v3 (R25): phase 1 scores -> Ps; ONE barrier; phase 2
// barrier-free PV with V fragments direct from global.
// ---------------------------------------------------------------------------
__global__ __launch_bounds__(256) void attn_fused_kernel(
    const uint* __restrict__ qh, const uint* __restrict__ kth,
    const ushort* __restrict__ vt, ushort* __restrict__ yb)
{
  __shared__ __align__(16) ushort Ps[16][520];
  const int tid = threadIdx.x;
  const int w = tid >> 6, lane = tid & 63;
  const int bx = blockIdx.x;
  const int h = bx & 15;
  const int ic = 31 - (bx >> 4);        // heavy chunks first
  const int g = h >> 1;
  const int i0 = ic * 16;
  const int njt = (i0 >> 6) + 1;

  const half2v NEGBIG = {(_Float16)-60000.0f, (_Float16)-60000.0f};
  for (int jt = 0; jt < njt; ++jt) {
    const int j0 = jt * 64;
    const bool diag = (jt == njt - 1);
    half2v kreg[32];
    const uint* ktp = &kth[g * 16384 + j0 + lane];
#pragma unroll
    for (int d2 = 0; d2 < 32; ++d2) kreg[d2] = bch2(ktp[d2 * 512]);
#pragma unroll
    for (int q = 0; q < 4; ++q) {
      const int lrow = w * 4 + q;
      const int row = i0 + lrow;
      const uint4* qp4 = reinterpret_cast<const uint4*>(&qh[(row * 16 + h) * 32]);
      half2v m0 = NEGBIG, m1 = NEGBIG;
#pragma unroll
      for (int it = 0; it < 8; ++it) {
        uint4 qq = qp4[it];
        half2v a0 = bch2(qq.x) + kreg[it * 4 + 0];
        half2v a1 = bch2(qq.y) + kreg[it * 4 + 1];
        half2v a2 = bch2(qq.z) + kreg[it * 4 + 2];
        half2v a3 = bch2(qq.w) + kreg[it * 4 + 3];
        m0 = __builtin_elementwise_max(m0, __builtin_elementwise_max(a0, a1));
        m1 = __builtin_elementwise_max(m1, __builtin_elementwise_max(a2, a3));
      }
      half2v mm = __builtin_elementwise_max(m0, m1);
      float s = fmaxf((float)mm[0], (float)mm[1]);
      if (diag && (j0 + lane > row)) s = -INFINITY;
      Ps[lrow][j0 + lane] = f2bf(__expf(s));
    }
  }
  __syncthreads();

  const int lr = lane & 15, lk8 = (lane >> 4) * 8;
  f32x4 acc = {}, accl = {};
  bf16x8 ones;
#pragma unroll
  for (int e = 0; e < 8; ++e) ones[e] = (short)0x3F80;
  const ushort* vrow = &vt[g * 32768 + (w * 16 + lr) * 512];

  for (int jt = 0; jt < njt; ++jt) {
    const int j0 = jt * 64;
#pragma unroll
    for (int kk = 0; kk < 2; ++kk) {
      bf16x8 af = *reinterpret_cast<const bf16x8*>(&Ps[lr][j0 + kk * 32 + lk8]);
      bf16x8 bg = *reinterpret_cast<const bf16x8*>(&vrow[j0 + kk * 32 + lk8]);
      acc  = __builtin_amdgcn_mfma_f32_16x16x32_bf16(af, bg, acc, 0, 0, 0);
      accl = __builtin_amdgcn_mfma_f32_16x16x32_bf16(af, ones, accl, 0, 0, 0);
    }
  }

  const int crow = (lane >> 4) * 4, ccol = lane & 15;
#pragma unroll
  for (int r = 0; r < 4; ++r) {
    int i = i0 + crow + r;
    yb[i * 1024 + h * 64 + w * 16 + ccol] = f2bf(acc[r] / accl[r]);
  }
}

// ---------------------------------------------------------------------------
// MEASUREMENT ROUND #4: 4 no-op kernels interleaved with the real pipeline.
// Delta vs R25 (45.9 us) = 4 x per-launch overhead. Everything else
// byte-identical to R25.
// ---------------------------------------------------------------------------
extern "C" void kernel_launch(void* const* d_in, const int* in_sizes, int n_in,
                              void* d_out, int out_size, void* d_ws, size_t ws_size,
                              hipStream_t stream) {
  const float* x    = (const float*)d_in[0];
  const float* cosb = (const float*)d_in[1];
  const float* sinb = (const float*)d_in[2];
  const float* Wq   = (const float*)d_in[3];
  const float* Wk   = (const float*)d_in[4];
  const float* Wv   = (const float*)d_in[5];
  const float* Wo   = (const float*)d_in[6];
  float* out = (float*)d_out;

  uint* wsu32 = (uint*)d_ws;
  uint*  kth  = wsu32;                     // 8x32x512 uint (half2 K^T)
  uint*  qh   = kth + 8 * 32 * 512;        // 512x16x32 uint (half2 q)
  ushort* xb  = (ushort*)(qh + TT * 16 * 32);  // 512x1024 bf16
  ushort* yb  = xb + TT * CC;              // 512x1024 bf16
  ushort* vtb = yb + TT * CC;              // 8x64x512 bf16 (V^T)
  ushort* Wtq = vtb + 8 * 64 * 512;        // 1024x1024 bf16
  ushort* Wtk = Wtq + CC * CC;             // 512x1024 bf16
  ushort* Wtv = Wtk + 512 * CC;            // 512x1024 bf16
  ushort* Wto = Wtv + 512 * CC;            // 1024x1024 bf16

  prep_kernel<<<dim3(1024), 256, 0, stream>>>(x, Wq, Wk, Wv, Wo, xb, Wtq, Wtk, Wtv, Wto);
  noop_kernel<<<dim3(1), 64, 0, stream>>>();                   // probe 1
  qkv_rope_kernel<<<dim3(32, 16), 256, 0, stream>>>(
      xb, Wtq, Wtk, Wtv, cosb, sinb, qh, kth, vtb);
  noop_kernel<<<dim3(1), 64, 0, stream>>>();                   // probe 2
  attn_fused_kernel<<<dim3(512), 256, 0, stream>>>(qh, kth, vtb, yb);
  noop_kernel<<<dim3(1), 64, 0, stream>>>();                   // probe 3
  out_mfma16_kernel<<<dim3(16, 32), 256, 0, stream>>>(yb, Wto, out);
  noop_kernel<<<dim3(1), 64, 0, stream>>>();                   // probe 4
}

// Round 27
// 46.431 us; speedup vs baseline: 1.1033x; 1.1033x over previous
//
#include <hip/hip_runtime.h>
#include <hip/hip_bf16.h>
#include <math.h>

#define TT 512
#define CC 1024
#define NH 16
#define NKV 8
#define HD 64
static constexpr float EPS_ = 1e-6f;

typedef short bf16x8 __attribute__((ext_vector_type(8)));
typedef float f32x4 __attribute__((ext_vector_type(4)));
typedef _Float16 half2v __attribute__((ext_vector_type(2)));

__device__ __forceinline__ ushort f2bf(float f) {
  union { __hip_bfloat16 h; ushort u; } cv;
  cv.h = __float2bfloat16(f);
  return cv.u;
}
__device__ __forceinline__ ushort f2h(float f) {
  union { _Float16 h; ushort u; } cv;
  cv.h = (_Float16)f;
  return cv.u;
}
__device__ __forceinline__ half2v bch2(uint u) {
  union { uint u; half2v h; } cv;
  cv.u = u;
  return cv.h;
}

// ---------------------------------------------------------------------------
// prep: x -> bf16 (same layout); Wq/Wk/Wv/Wo -> transposed bf16 Wt[n][k]
// ---------------------------------------------------------------------------
__global__ __launch_bounds__(256) void prep_kernel(
    const float* __restrict__ x,
    const float* __restrict__ Wq, const float* __restrict__ Wk,
    const float* __restrict__ Wv, const float* __restrict__ Wo,
    ushort* __restrict__ xb, ushort* __restrict__ Wtq, ushort* __restrict__ Wtk,
    ushort* __restrict__ Wtv, ushort* __restrict__ Wto)
{
  int b = blockIdx.x;
  if (b < 256) {
    int base = b * 2048 + threadIdx.x * 8;
    float4 f0 = *reinterpret_cast<const float4*>(&x[base]);
    float4 f1 = *reinterpret_cast<const float4*>(&x[base + 4]);
    union { ushort u[8]; uint4 v; } pk;
    pk.u[0] = f2bf(f0.x); pk.u[1] = f2bf(f0.y); pk.u[2] = f2bf(f0.z); pk.u[3] = f2bf(f0.w);
    pk.u[4] = f2bf(f1.x); pk.u[5] = f2bf(f1.y); pk.u[6] = f2bf(f1.z); pk.u[7] = f2bf(f1.w);
    *reinterpret_cast<uint4*>(&xb[base]) = pk.v;
    return;
  }
  b -= 256;
  const float* W; ushort* Wt; int ldW, tr, tc;
  if (b < 256)      { W = Wq; Wt = Wtq; ldW = 1024; tr = b >> 4;       tc = b & 15; }
  else if (b < 384) { int q = b - 256; W = Wk; Wt = Wtk; ldW = 512; tr = q >> 3; tc = q & 7; }
  else if (b < 512) { int q = b - 384; W = Wv; Wt = Wtv; ldW = 512; tr = q >> 3; tc = q & 7; }
  else              { int q = b - 512; W = Wo; Wt = Wto; ldW = 1024; tr = q >> 4; tc = q & 15; }
  const int k0 = tr * 64, n0 = tc * 64;
  __shared__ float ft[64][65];
  const int t = threadIdx.x;
#pragma unroll
  for (int it = 0; it < 4; ++it) {
    int q = t + it * 256;
    int r = q >> 4, c4 = q & 15;
    float4 f = *reinterpret_cast<const float4*>(&W[(k0 + r) * ldW + n0 + c4 * 4]);
    ft[r][c4 * 4 + 0] = f.x; ft[r][c4 * 4 + 1] = f.y;
    ft[r][c4 * 4 + 2] = f.z; ft[r][c4 * 4 + 3] = f.w;
  }
  __syncthreads();
#pragma unroll
  for (int it = 0; it < 2; ++it) {
    int q = t + it * 256;
    int n = q >> 3, kc = q & 7;
    union { ushort u[8]; uint4 v; } pk;
#pragma unroll
    for (int j = 0; j < 8; ++j) pk.u[j] = f2bf(ft[kc * 8 + j][n]);
    *reinterpret_cast<uint4*>(&Wt[(n0 + n) * 1024 + k0 + kc * 8]) = pk.v;
  }
}

// ---------------------------------------------------------------------------
// Fused QKV GEMM + rope/rms/pack epilogue (R23-proven). 32x64 tiles,
// grid (32,16) = 512 blocks, BK=128.
// ---------------------------------------------------------------------------
__global__ __launch_bounds__(256) void qkv_rope_kernel(
    const ushort* __restrict__ xb,
    const ushort* __restrict__ Wtq, const ushort* __restrict__ Wtk, const ushort* __restrict__ Wtv,
    const float* __restrict__ cosb, const float* __restrict__ sinb,
    uint* __restrict__ qh, uint* __restrict__ kth, ushort* __restrict__ vt)
{
  __shared__ ushort At[32][136];
  __shared__ ushort Bs[64][136];
  __shared__ float ft[32][65];
  const int tid = threadIdx.x;
  const int lane = tid & 63, w = tid >> 6;
  const int bx = blockIdx.x, by = blockIdx.y;
  const int row0 = by * 32;

  const ushort* Bt; int col0;
  if (bx < 16)      { Bt = Wtq; col0 = bx * 64; }
  else if (bx < 24) { Bt = Wtk; col0 = (bx - 16) * 64; }
  else              { Bt = Wtv; col0 = (bx - 24) * 64; }

  const int m0 = (w & 1) * 16, n0 = (w >> 1) * 32;
  const int lr = lane & 15, lk = (lane >> 4) * 8;
  f32x4 acc[2] = {};
  const int srA = tid >> 3, scA = (tid & 7) * 16;
  const int srB = tid >> 2, scB = (tid & 3) * 32;
  const ushort* Ap = &xb[(row0 + srA) * 1024 + scA];
  const ushort* Bp = &Bt[(col0 + srB) * 1024 + scB];

  for (int k0 = 0; k0 < 1024; k0 += 128) {
    __syncthreads();
    uint4 a0 = *reinterpret_cast<const uint4*>(Ap + k0);
    uint4 a1 = *reinterpret_cast<const uint4*>(Ap + k0 + 8);
    uint4 b0 = *reinterpret_cast<const uint4*>(Bp + k0);
    uint4 b1 = *reinterpret_cast<const uint4*>(Bp + k0 + 8);
    uint4 b2 = *reinterpret_cast<const uint4*>(Bp + k0 + 16);
    uint4 b3 = *reinterpret_cast<const uint4*>(Bp + k0 + 24);
    *reinterpret_cast<uint4*>(&At[srA][scA]) = a0;
    *reinterpret_cast<uint4*>(&At[srA][scA + 8]) = a1;
    *reinterpret_cast<uint4*>(&Bs[srB][scB]) = b0;
    *reinterpret_cast<uint4*>(&Bs[srB][scB + 8]) = b1;
    *reinterpret_cast<uint4*>(&Bs[srB][scB + 16]) = b2;
    *reinterpret_cast<uint4*>(&Bs[srB][scB + 24]) = b3;
    __syncthreads();
#pragma unroll
    for (int kk = 0; kk < 4; ++kk) {
      bf16x8 af = *reinterpret_cast<const bf16x8*>(&At[m0 + lr][kk * 32 + lk]);
#pragma unroll
      for (int ni = 0; ni < 2; ++ni) {
        bf16x8 bg = *reinterpret_cast<const bf16x8*>(&Bs[n0 + ni * 16 + lr][kk * 32 + lk]);
        acc[ni] = __builtin_amdgcn_mfma_f32_16x16x32_bf16(af, bg, acc[ni], 0, 0, 0);
      }
    }
  }

  const int crow = (lane >> 4) * 4, ccol = lane & 15;
  __syncthreads();
#pragma unroll
  for (int ni = 0; ni < 2; ++ni)
#pragma unroll
    for (int r = 0; r < 4; ++r)
      ft[m0 + crow + r][n0 + ni * 16 + ccol] = acc[ni][r];
  __syncthreads();

  if (bx < 16) {                         // q: rope+rms -> packed half2 qh
    const int h = bx;
#pragma unroll 2
    for (int rr = 0; rr < 8; ++rr) {
      int row = w * 8 + rr;
      int t = row0 + row;
      float vv = ft[row][lane];
      float pt = ft[row][lane ^ 32];
      int f = lane & 31;
      float c = cosb[t * 32 + f], s = sinb[t * 32 + f];
      float o = (lane < 32) ? (vv * c - pt * s) : (pt * s + vv * c);
      float ss = o * o;
#pragma unroll
      for (int off = 32; off; off >>= 1) ss += __shfl_xor(ss, off);
      float rN = rsqrtf(ss * (1.0f / 64.0f) + EPS_);
      uint hv = (uint)f2h(o * rN);
      uint nb = __shfl_down(hv, 1);
      if ((lane & 1) == 0)
        qh[(t * 16 + h) * 32 + (lane >> 1)] = hv | (nb << 16);
    }
    return;
  }
  if (bx < 24) {                         // k: rope+rms -> packed half2 K^T
    const int g = bx - 16;
#pragma unroll 2
    for (int rr = 0; rr < 8; ++rr) {
      int row = w * 8 + rr;
      int t = row0 + row;
      float vv = ft[row][lane];
      float pt = ft[row][lane ^ 32];
      int f = lane & 31;
      float c = cosb[t * 32 + f], s = sinb[t * 32 + f];
      float o = (lane < 32) ? (vv * c - pt * s) : (pt * s + vv * c);
      float ss = o * o;
#pragma unroll
      for (int off = 32; off; off >>= 1) ss += __shfl_xor(ss, off);
      ft[row][lane] = o * rsqrtf(ss * (1.0f / 64.0f) + EPS_);
    }
    __syncthreads();
#pragma unroll
    for (int it = 0; it < 4; ++it) {
      int idx2 = tid + it * 256;
      int d2 = idx2 >> 5, tt = idx2 & 31;
      uint lo = (uint)f2h(ft[tt][2 * d2]);
      uint hi = (uint)f2h(ft[tt][2 * d2 + 1]);
      kth[g * 16384 + d2 * 512 + row0 + tt] = lo | (hi << 16);
    }
    return;
  }
  // v: convert + transpose -> vt (bf16)
  const int g = bx - 24;
#pragma unroll
  for (int it = 0; it < 4; ++it) {
    int idx2 = tid + it * 256;
    int d = idx2 >> 4, tp = idx2 & 15;
    uint o = (uint)f2bf(ft[tp * 2][d]) | ((uint)f2bf(ft[tp * 2 + 1][d]) << 16);
    *reinterpret_cast<uint*>(&vt[g * 32768 + d * 512 + row0 + tp * 2]) = o;
  }
}

// ---------------------------------------------------------------------------
// out GEMM, 16x64 tiles: grid (16,32) = 512 blocks (R23-proven).
// ---------------------------------------------------------------------------
__global__ __launch_bounds__(256) void out_mfma16_kernel(
    const ushort* __restrict__ yb, const ushort* __restrict__ Wto, float* __restrict__ out)
{
  __shared__ ushort At[16][72];
  __shared__ ushort Bs[64][72];
  const int tid = threadIdx.x;
  const int lane = tid & 63, w = tid >> 6;
  const int row0 = blockIdx.y * 16, col0 = blockIdx.x * 64;
  const int lr = lane & 15, lk = (lane >> 4) * 8;
  f32x4 acc = {};
  const int srA = tid >> 4, scA = (tid & 15) * 4;
  const int srB = tid >> 2, scB = (tid & 3) * 16;
  const ushort* Ap = &yb[(row0 + srA) * 1024 + scA];
  const ushort* Bp = &Wto[(col0 + srB) * 1024 + scB];

  for (int k0 = 0; k0 < 1024; k0 += 64) {
    __syncthreads();
    uint2 a0 = *reinterpret_cast<const uint2*>(Ap + k0);
    uint4 b0 = *reinterpret_cast<const uint4*>(Bp + k0);
    uint4 b1 = *reinterpret_cast<const uint4*>(Bp + k0 + 8);
    *reinterpret_cast<uint2*>(&At[srA][scA]) = a0;
    *reinterpret_cast<uint4*>(&Bs[srB][scB]) = b0;
    *reinterpret_cast<uint4*>(&Bs[srB][scB + 8]) = b1;
    __syncthreads();
#pragma unroll
    for (int kk = 0; kk < 2; ++kk) {
      bf16x8 af = *reinterpret_cast<const bf16x8*>(&At[lr][kk * 32 + lk]);
      bf16x8 bg = *reinterpret_cast<const bf16x8*>(&Bs[w * 16 + lr][kk * 32 + lk]);
      acc = __builtin_amdgcn_mfma_f32_16x16x32_bf16(af, bg, acc, 0, 0, 0);
    }
  }
  const int crow = (lane >> 4) * 4, ccol = lane & 15;
#pragma unroll
  for (int r = 0; r < 4; ++r)
    out[(row0 + crow + r) * 1024 + col0 + w * 16 + ccol] = acc[r];
}

// ---------------------------------------------------------------------------
// Fused attention v4: phase 1 with DOUBLE-BUFFERED kreg prefetch — tile
// jt+1's K-columns load while tile jt computes (hides L2 latency on the
// serial j-loop critical path). Phase 2 unchanged (barrier-free direct-V).
// ---------------------------------------------------------------------------
__global__ __launch_bounds__(256) void attn_fused_kernel(
    const uint* __restrict__ qh, const uint* __restrict__ kth,
    const ushort* __restrict__ vt, ushort* __restrict__ yb)
{
  __shared__ __align__(16) ushort Ps[16][520];
  const int tid = threadIdx.x;
  const int w = tid >> 6, lane = tid & 63;
  const int bx = blockIdx.x;
  const int h = bx & 15;
  const int ic = 31 - (bx >> 4);        // heavy chunks first
  const int g = h >> 1;
  const int i0 = ic * 16;
  const int njt = (i0 >> 6) + 1;

  // ---- phase 1: scores + exp -> Ps, double-buffered kreg
  const half2v NEGBIG = {(_Float16)-60000.0f, (_Float16)-60000.0f};
  const uint* kbase = &kth[g * 16384 + lane];
  half2v kregA[32], kregB[32];
#pragma unroll
  for (int d2 = 0; d2 < 32; ++d2) kregA[d2] = bch2(kbase[d2 * 512]);

  for (int jt = 0; jt < njt; ++jt) {
    // prefetch next tile while this tile computes
    if (jt + 1 < njt) {
      const uint* knext = kbase + (jt + 1) * 64;
#pragma unroll
      for (int d2 = 0; d2 < 32; ++d2) kregB[d2] = bch2(knext[d2 * 512]);
    }
    const int j0 = jt * 64;
    const bool diag = (jt == njt - 1);
#pragma unroll
    for (int q = 0; q < 4; ++q) {
      const int lrow = w * 4 + q;
      const int row = i0 + lrow;
      const uint4* qp4 = reinterpret_cast<const uint4*>(&qh[(row * 16 + h) * 32]);
      half2v m0 = NEGBIG, m1 = NEGBIG;
#pragma unroll
      for (int it = 0; it < 8; ++it) {
        uint4 qq = qp4[it];
        half2v a0 = bch2(qq.x) + kregA[it * 4 + 0];
        half2v a1 = bch2(qq.y) + kregA[it * 4 + 1];
        half2v a2 = bch2(qq.z) + kregA[it * 4 + 2];
        half2v a3 = bch2(qq.w) + kregA[it * 4 + 3];
        m0 = __builtin_elementwise_max(m0, __builtin_elementwise_max(a0, a1));
        m1 = __builtin_elementwise_max(m1, __builtin_elementwise_max(a2, a3));
      }
      half2v mm = __builtin_elementwise_max(m0, m1);
      float s = fmaxf((float)mm[0], (float)mm[1]);
      if (diag && (j0 + lane > row)) s = -INFINITY;
      Ps[lrow][j0 + lane] = f2bf(__expf(s));
    }
    // rotate buffers (register moves, fully static indexing)
#pragma unroll
    for (int d2 = 0; d2 < 32; ++d2) kregA[d2] = kregB[d2];
  }
  __syncthreads();                      // Ps complete

  // ---- phase 2: y = (P @ V) / rowsum(P); V fragments direct from global
  const int lr = lane & 15, lk8 = (lane >> 4) * 8;
  f32x4 acc = {}, accl = {};
  bf16x8 ones;
#pragma unroll
  for (int e = 0; e < 8; ++e) ones[e] = (short)0x3F80;
  const ushort* vrow = &vt[g * 32768 + (w * 16 + lr) * 512];

  for (int jt = 0; jt < njt; ++jt) {
    const int j0 = jt * 64;
#pragma unroll
    for (int kk = 0; kk < 2; ++kk) {
      bf16x8 af = *reinterpret_cast<const bf16x8*>(&Ps[lr][j0 + kk * 32 + lk8]);
      bf16x8 bg = *reinterpret_cast<const bf16x8*>(&vrow[j0 + kk * 32 + lk8]);
      acc  = __builtin_amdgcn_mfma_f32_16x16x32_bf16(af, bg, acc, 0, 0, 0);
      accl = __builtin_amdgcn_mfma_f32_16x16x32_bf16(af, ones, accl, 0, 0, 0);
    }
  }

  const int crow = (lane >> 4) * 4, ccol = lane & 15;
#pragma unroll
  for (int r = 0; r < 4; ++r) {
    int i = i0 + crow + r;
    yb[i * 1024 + h * 64 + w * 16 + ccol] = f2bf(acc[r] / accl[r]);
  }
}

// ---------------------------------------------------------------------------
extern "C" void kernel_launch(void* const* d_in, const int* in_sizes, int n_in,
                              void* d_out, int out_size, void* d_ws, size_t ws_size,
                              hipStream_t stream) {
  const float* x    = (const float*)d_in[0];
  const float* cosb = (const float*)d_in[1];
  const float* sinb = (const float*)d_in[2];
  const float* Wq   = (const float*)d_in[3];
  const float* Wk   = (const float*)d_in[4];
  const float* Wv   = (const float*)d_in[5];
  const float* Wo   = (const float*)d_in[6];
  float* out = (float*)d_out;

  uint* wsu32 = (uint*)d_ws;
  uint*  kth  = wsu32;                     // 8x32x512 uint (half2 K^T)
  uint*  qh   = kth + 8 * 32 * 512;        // 512x16x32 uint (half2 q)
  ushort* xb  = (ushort*)(qh + TT * 16 * 32);  // 512x1024 bf16
  ushort* yb  = xb + TT * CC;              // 512x1024 bf16
  ushort* vtb = yb + TT * CC;              // 8x64x512 bf16 (V^T)
  ushort* Wtq = vtb + 8 * 64 * 512;        // 1024x1024 bf16
  ushort* Wtk = Wtq + CC * CC;             // 512x1024 bf16
  ushort* Wtv = Wtk + 512 * CC;            // 512x1024 bf16
  ushort* Wto = Wtv + 512 * CC;            // 1024x1024 bf16

  prep_kernel<<<dim3(1024), 256, 0, stream>>>(x, Wq, Wk, Wv, Wo, xb, Wtq, Wtk, Wtv, Wto);
  qkv_rope_kernel<<<dim3(32, 16), 256, 0, stream>>>(
      xb, Wtq, Wtk, Wtv, cosb, sinb, qh, kth, vtb);
  attn_fused_kernel<<<dim3(512), 256, 0, stream>>>(qh, kth, vtb, yb);
  out_mfma16_kernel<<<dim3(16, 32), 256, 0, stream>>>(yb, Wto, out);
}

// Round 28
// 43.353 us; speedup vs baseline: 1.1816x; 1.0710x over previous
//
#include <hip/hip_runtime.h>
#include <hip/hip_bf16.h>
#include <math.h>

#define TT 512
#define CC 1024
#define NH 16
#define NKV 8
#define HD 64
static constexpr float EPS_ = 1e-6f;

typedef short bf16x8 __attribute__((ext_vector_type(8)));
typedef float f32x4 __attribute__((ext_vector_type(4)));
typedef _Float16 half2v __attribute__((ext_vector_type(2)));

__device__ __forceinline__ ushort f2bf(float f) {
  union { __hip_bfloat16 h; ushort u; } cv;
  cv.h = __float2bfloat16(f);
  return cv.u;
}
__device__ __forceinline__ ushort f2h(float f) {
  union { _Float16 h; ushort u; } cv;
  cv.h = (_Float16)f;
  return cv.u;
}
__device__ __forceinline__ half2v bch2(uint u) {
  union { uint u; half2v h; } cv;
  cv.u = u;
  return cv.h;
}

// ---------------------------------------------------------------------------
// prep: x -> bf16 (same layout); Wq/Wk/Wv/Wo -> transposed bf16 Wt[n][k]
// ---------------------------------------------------------------------------
__global__ __launch_bounds__(256) void prep_kernel(
    const float* __restrict__ x,
    const float* __restrict__ Wq, const float* __restrict__ Wk,
    const float* __restrict__ Wv, const float* __restrict__ Wo,
    ushort* __restrict__ xb, ushort* __restrict__ Wtq, ushort* __restrict__ Wtk,
    ushort* __restrict__ Wtv, ushort* __restrict__ Wto)
{
  int b = blockIdx.x;
  if (b < 256) {
    int base = b * 2048 + threadIdx.x * 8;
    float4 f0 = *reinterpret_cast<const float4*>(&x[base]);
    float4 f1 = *reinterpret_cast<const float4*>(&x[base + 4]);
    union { ushort u[8]; uint4 v; } pk;
    pk.u[0] = f2bf(f0.x); pk.u[1] = f2bf(f0.y); pk.u[2] = f2bf(f0.z); pk.u[3] = f2bf(f0.w);
    pk.u[4] = f2bf(f1.x); pk.u[5] = f2bf(f1.y); pk.u[6] = f2bf(f1.z); pk.u[7] = f2bf(f1.w);
    *reinterpret_cast<uint4*>(&xb[base]) = pk.v;
    return;
  }
  b -= 256;
  const float* W; ushort* Wt; int ldW, tr, tc;
  if (b < 256)      { W = Wq; Wt = Wtq; ldW = 1024; tr = b >> 4;       tc = b & 15; }
  else if (b < 384) { int q = b - 256; W = Wk; Wt = Wtk; ldW = 512; tr = q >> 3; tc = q & 7; }
  else if (b < 512) { int q = b - 384; W = Wv; Wt = Wtv; ldW = 512; tr = q >> 3; tc = q & 7; }
  else              { int q = b - 512; W = Wo; Wt = Wto; ldW = 1024; tr = q >> 4; tc = q & 15; }
  const int k0 = tr * 64, n0 = tc * 64;
  __shared__ float ft[64][65];
  const int t = threadIdx.x;
#pragma unroll
  for (int it = 0; it < 4; ++it) {
    int q = t + it * 256;
    int r = q >> 4, c4 = q & 15;
    float4 f = *reinterpret_cast<const float4*>(&W[(k0 + r) * ldW + n0 + c4 * 4]);
    ft[r][c4 * 4 + 0] = f.x; ft[r][c4 * 4 + 1] = f.y;
    ft[r][c4 * 4 + 2] = f.z; ft[r][c4 * 4 + 3] = f.w;
  }
  __syncthreads();
#pragma unroll
  for (int it = 0; it < 2; ++it) {
    int q = t + it * 256;
    int n = q >> 3, kc = q & 7;
    union { ushort u[8]; uint4 v; } pk;
#pragma unroll
    for (int j = 0; j < 8; ++j) pk.u[j] = f2bf(ft[kc * 8 + j][n]);
    *reinterpret_cast<uint4*>(&Wt[(n0 + n) * 1024 + k0 + kc * 8]) = pk.v;
  }
}

// ---------------------------------------------------------------------------
// Fused QKV GEMM + rope/rms/pack epilogue with async-STAGE split (T14):
// next K-step's global loads issue right after the "LDS ready" barrier so
// their latency hides under the MFMA phase. 32x64 tiles, grid (32,16),
// BK=128.
// ---------------------------------------------------------------------------
__global__ __launch_bounds__(256) void qkv_rope_kernel(
    const ushort* __restrict__ xb,
    const ushort* __restrict__ Wtq, const ushort* __restrict__ Wtk, const ushort* __restrict__ Wtv,
    const float* __restrict__ cosb, const float* __restrict__ sinb,
    uint* __restrict__ qh, uint* __restrict__ kth, ushort* __restrict__ vt)
{
  __shared__ ushort At[32][136];
  __shared__ ushort Bs[64][136];
  __shared__ float ft[32][65];
  const int tid = threadIdx.x;
  const int lane = tid & 63, w = tid >> 6;
  const int bx = blockIdx.x, by = blockIdx.y;
  const int row0 = by * 32;

  const ushort* Bt; int col0;
  if (bx < 16)      { Bt = Wtq; col0 = bx * 64; }
  else if (bx < 24) { Bt = Wtk; col0 = (bx - 16) * 64; }
  else              { Bt = Wtv; col0 = (bx - 24) * 64; }

  const int m0 = (w & 1) * 16, n0 = (w >> 1) * 32;
  const int lr = lane & 15, lk = (lane >> 4) * 8;
  f32x4 acc[2] = {};
  const int srA = tid >> 3, scA = (tid & 7) * 16;
  const int srB = tid >> 2, scB = (tid & 3) * 32;
  const ushort* Ap = &xb[(row0 + srA) * 1024 + scA];
  const ushort* Bp = &Bt[(col0 + srB) * 1024 + scB];

  // prologue: stage K-step 0 into registers
  uint4 a0 = *reinterpret_cast<const uint4*>(Ap);
  uint4 a1 = *reinterpret_cast<const uint4*>(Ap + 8);
  uint4 b0 = *reinterpret_cast<const uint4*>(Bp);
  uint4 b1 = *reinterpret_cast<const uint4*>(Bp + 8);
  uint4 b2 = *reinterpret_cast<const uint4*>(Bp + 16);
  uint4 b3 = *reinterpret_cast<const uint4*>(Bp + 24);

  for (int k0 = 0; k0 < 1024; k0 += 128) {
    __syncthreads();                     // prev compute done; LDS reusable
    *reinterpret_cast<uint4*>(&At[srA][scA]) = a0;
    *reinterpret_cast<uint4*>(&At[srA][scA + 8]) = a1;
    *reinterpret_cast<uint4*>(&Bs[srB][scB]) = b0;
    *reinterpret_cast<uint4*>(&Bs[srB][scB + 8]) = b1;
    *reinterpret_cast<uint4*>(&Bs[srB][scB + 16]) = b2;
    *reinterpret_cast<uint4*>(&Bs[srB][scB + 24]) = b3;
    __syncthreads();                     // LDS ready
    if (k0 + 128 < 1024) {               // issue next loads; fly under MFMA
      a0 = *reinterpret_cast<const uint4*>(Ap + k0 + 128);
      a1 = *reinterpret_cast<const uint4*>(Ap + k0 + 136);
      b0 = *reinterpret_cast<const uint4*>(Bp + k0 + 128);
      b1 = *reinterpret_cast<const uint4*>(Bp + k0 + 136);
      b2 = *reinterpret_cast<const uint4*>(Bp + k0 + 144);
      b3 = *reinterpret_cast<const uint4*>(Bp + k0 + 152);
    }
#pragma unroll
    for (int kk = 0; kk < 4; ++kk) {
      bf16x8 af = *reinterpret_cast<const bf16x8*>(&At[m0 + lr][kk * 32 + lk]);
#pragma unroll
      for (int ni = 0; ni < 2; ++ni) {
        bf16x8 bg = *reinterpret_cast<const bf16x8*>(&Bs[n0 + ni * 16 + lr][kk * 32 + lk]);
        acc[ni] = __builtin_amdgcn_mfma_f32_16x16x32_bf16(af, bg, acc[ni], 0, 0, 0);
      }
    }
  }

  const int crow = (lane >> 4) * 4, ccol = lane & 15;
  __syncthreads();
#pragma unroll
  for (int ni = 0; ni < 2; ++ni)
#pragma unroll
    for (int r = 0; r < 4; ++r)
      ft[m0 + crow + r][n0 + ni * 16 + ccol] = acc[ni][r];
  __syncthreads();

  if (bx < 16) {                         // q: rope+rms -> packed half2 qh
    const int h = bx;
#pragma unroll 2
    for (int rr = 0; rr < 8; ++rr) {
      int row = w * 8 + rr;
      int t = row0 + row;
      float vv = ft[row][lane];
      float pt = ft[row][lane ^ 32];
      int f = lane & 31;
      float c = cosb[t * 32 + f], s = sinb[t * 32 + f];
      float o = (lane < 32) ? (vv * c - pt * s) : (pt * s + vv * c);
      float ss = o * o;
#pragma unroll
      for (int off = 32; off; off >>= 1) ss += __shfl_xor(ss, off);
      float rN = rsqrtf(ss * (1.0f / 64.0f) + EPS_);
      uint hv = (uint)f2h(o * rN);
      uint nb = __shfl_down(hv, 1);
      if ((lane & 1) == 0)
        qh[(t * 16 + h) * 32 + (lane >> 1)] = hv | (nb << 16);
    }
    return;
  }
  if (bx < 24) {                         // k: rope+rms -> packed half2 K^T
    const int g = bx - 16;
#pragma unroll 2
    for (int rr = 0; rr < 8; ++rr) {
      int row = w * 8 + rr;
      int t = row0 + row;
      float vv = ft[row][lane];
      float pt = ft[row][lane ^ 32];
      int f = lane & 31;
      float c = cosb[t * 32 + f], s = sinb[t * 32 + f];
      float o = (lane < 32) ? (vv * c - pt * s) : (pt * s + vv * c);
      float ss = o * o;
#pragma unroll
      for (int off = 32; off; off >>= 1) ss += __shfl_xor(ss, off);
      ft[row][lane] = o * rsqrtf(ss * (1.0f / 64.0f) + EPS_);
    }
    __syncthreads();
#pragma unroll
    for (int it = 0; it < 4; ++it) {
      int idx2 = tid + it * 256;
      int d2 = idx2 >> 5, tt = idx2 & 31;
      uint lo = (uint)f2h(ft[tt][2 * d2]);
      uint hi = (uint)f2h(ft[tt][2 * d2 + 1]);
      kth[g * 16384 + d2 * 512 + row0 + tt] = lo | (hi << 16);
    }
    return;
  }
  // v: convert + transpose -> vt (bf16)
  const int g = bx - 24;
#pragma unroll
  for (int it = 0; it < 4; ++it) {
    int idx2 = tid + it * 256;
    int d = idx2 >> 4, tp = idx2 & 15;
    uint o = (uint)f2bf(ft[tp * 2][d]) | ((uint)f2bf(ft[tp * 2 + 1][d]) << 16);
    *reinterpret_cast<uint*>(&vt[g * 32768 + d * 512 + row0 + tp * 2]) = o;
  }
}

// ---------------------------------------------------------------------------
// out GEMM, 16x64 tiles with async-STAGE split (T14). grid (16,32).
// ---------------------------------------------------------------------------
__global__ __launch_bounds__(256) void out_mfma16_kernel(
    const ushort* __restrict__ yb, const ushort* __restrict__ Wto, float* __restrict__ out)
{
  __shared__ ushort At[16][72];
  __shared__ ushort Bs[64][72];
  const int tid = threadIdx.x;
  const int lane = tid & 63, w = tid >> 6;
  const int row0 = blockIdx.y * 16, col0 = blockIdx.x * 64;
  const int lr = lane & 15, lk = (lane >> 4) * 8;
  f32x4 acc = {};
  const int srA = tid >> 4, scA = (tid & 15) * 4;
  const int srB = tid >> 2, scB = (tid & 3) * 16;
  const ushort* Ap = &yb[(row0 + srA) * 1024 + scA];
  const ushort* Bp = &Wto[(col0 + srB) * 1024 + scB];

  // prologue: stage K-step 0 into registers
  uint2 a0 = *reinterpret_cast<const uint2*>(Ap);
  uint4 b0 = *reinterpret_cast<const uint4*>(Bp);
  uint4 b1 = *reinterpret_cast<const uint4*>(Bp + 8);

  for (int k0 = 0; k0 < 1024; k0 += 64) {
    __syncthreads();
    *reinterpret_cast<uint2*>(&At[srA][scA]) = a0;
    *reinterpret_cast<uint4*>(&Bs[srB][scB]) = b0;
    *reinterpret_cast<uint4*>(&Bs[srB][scB + 8]) = b1;
    __syncthreads();
    if (k0 + 64 < 1024) {                // issue next loads; fly under MFMA
      a0 = *reinterpret_cast<const uint2*>(Ap + k0 + 64);
      b0 = *reinterpret_cast<const uint4*>(Bp + k0 + 64);
      b1 = *reinterpret_cast<const uint4*>(Bp + k0 + 72);
    }
#pragma unroll
    for (int kk = 0; kk < 2; ++kk) {
      bf16x8 af = *reinterpret_cast<const bf16x8*>(&At[lr][kk * 32 + lk]);
      bf16x8 bg = *reinterpret_cast<const bf16x8*>(&Bs[w * 16 + lr][kk * 32 + lk]);
      acc = __builtin_amdgcn_mfma_f32_16x16x32_bf16(af, bg, acc, 0, 0, 0);
    }
  }
  const int crow = (lane >> 4) * 4, ccol = lane & 15;
#pragma unroll
  for (int r = 0; r < 4; ++r)
    out[(row0 + crow + r) * 1024 + col0 + w * 16 + ccol] = acc[r];
}

// ---------------------------------------------------------------------------
// Fused attention v3 (R25-proven): phase 1 scores -> Ps; ONE barrier; phase 2
// barrier-free PV with V fragments direct from global.
// ---------------------------------------------------------------------------
__global__ __launch_bounds__(256) void attn_fused_kernel(
    const uint* __restrict__ qh, const uint* __restrict__ kth,
    const ushort* __restrict__ vt, ushort* __restrict__ yb)
{
  __shared__ __align__(16) ushort Ps[16][520];
  const int tid = threadIdx.x;
  const int w = tid >> 6, lane = tid & 63;
  const int bx = blockIdx.x;
  const int h = bx & 15;
  const int ic = 31 - (bx >> 4);        // heavy chunks first
  const int g = h >> 1;
  const int i0 = ic * 16;
  const int njt = (i0 >> 6) + 1;

  const half2v NEGBIG = {(_Float16)-60000.0f, (_Float16)-60000.0f};
  for (int jt = 0; jt < njt; ++jt) {
    const int j0 = jt * 64;
    const bool diag = (jt == njt - 1);
    half2v kreg[32];
    const uint* ktp = &kth[g * 16384 + j0 + lane];
#pragma unroll
    for (int d2 = 0; d2 < 32; ++d2) kreg[d2] = bch2(ktp[d2 * 512]);
#pragma unroll
    for (int q = 0; q < 4; ++q) {
      const int lrow = w * 4 + q;
      const int row = i0 + lrow;
      const uint4* qp4 = reinterpret_cast<const uint4*>(&qh[(row * 16 + h) * 32]);
      half2v m0 = NEGBIG, m1 = NEGBIG;
#pragma unroll
      for (int it = 0; it < 8; ++it) {
        uint4 qq = qp4[it];
        half2v a0 = bch2(qq.x) + kreg[it * 4 + 0];
        half2v a1 = bch2(qq.y) + kreg[it * 4 + 1];
        half2v a2 = bch2(qq.z) + kreg[it * 4 + 2];
        half2v a3 = bch2(qq.w) + kreg[it * 4 + 3];
        m0 = __builtin_elementwise_max(m0, __builtin_elementwise_max(a0, a1));
        m1 = __builtin_elementwise_max(m1, __builtin_elementwise_max(a2, a3));
      }
      half2v mm = __builtin_elementwise_max(m0, m1);
      float s = fmaxf((float)mm[0], (float)mm[1]);
      if (diag && (j0 + lane > row)) s = -INFINITY;
      Ps[lrow][j0 + lane] = f2bf(__expf(s));
    }
  }
  __syncthreads();

  const int lr = lane & 15, lk8 = (lane >> 4) * 8;
  f32x4 acc = {}, accl = {};
  bf16x8 ones;
#pragma unroll
  for (int e = 0; e < 8; ++e) ones[e] = (short)0x3F80;
  const ushort* vrow = &vt[g * 32768 + (w * 16 + lr) * 512];

  for (int jt = 0; jt < njt; ++jt) {
    const int j0 = jt * 64;
#pragma unroll
    for (int kk = 0; kk < 2; ++kk) {
      bf16x8 af = *reinterpret_cast<const bf16x8*>(&Ps[lr][j0 + kk * 32 + lk8]);
      bf16x8 bg = *reinterpret_cast<const bf16x8*>(&vrow[j0 + kk * 32 + lk8]);
      acc  = __builtin_amdgcn_mfma_f32_16x16x32_bf16(af, bg, acc, 0, 0, 0);
      accl = __builtin_amdgcn_mfma_f32_16x16x32_bf16(af, ones, accl, 0, 0, 0);
    }
  }

  const int crow = (lane >> 4) * 4, ccol = lane & 15;
#pragma unroll
  for (int r = 0; r < 4; ++r) {
    int i = i0 + crow + r;
    yb[i * 1024 + h * 64 + w * 16 + ccol] = f2bf(acc[r] / accl[r]);
  }
}

// ---------------------------------------------------------------------------
extern "C" void kernel_launch(void* const* d_in, const int* in_sizes, int n_in,
                              void* d_out, int out_size, void* d_ws, size_t ws_size,
                              hipStream_t stream) {
  const float* x    = (const float*)d_in[0];
  const float* cosb = (const float*)d_in[1];
  const float* sinb = (const float*)d_in[2];
  const float* Wq   = (const float*)d_in[3];
  const float* Wk   = (const float*)d_in[4];
  const float* Wv   = (const float*)d_in[5];
  const float* Wo   = (const float*)d_in[6];
  float* out = (float*)d_out;

  uint* wsu32 = (uint*)d_ws;
  uint*  kth  = wsu32;                     // 8x32x512 uint (half2 K^T)
  uint*  qh   = kth + 8 * 32 * 512;        // 512x16x32 uint (half2 q)
  ushort* xb  = (ushort*)(qh + TT * 16 * 32);  // 512x1024 bf16
  ushort* yb  = xb + TT * CC;              // 512x1024 bf16
  ushort* vtb = yb + TT * CC;              // 8x64x512 bf16 (V^T)
  ushort* Wtq = vtb + 8 * 64 * 512;        // 1024x1024 bf16
  ushort* Wtk = Wtq + CC * CC;             // 512x1024 bf16
  ushort* Wtv = Wtk + 512 * CC;            // 512x1024 bf16
  ushort* Wto = Wtv + 512 * CC;            // 1024x1024 bf16

  prep_kernel<<<dim3(1024), 256, 0, stream>>>(x, Wq, Wk, Wv, Wo, xb, Wtq, Wtk, Wtv, Wto);
  qkv_rope_kernel<<<dim3(32, 16), 256, 0, stream>>>(
      xb, Wtq, Wtk, Wtv, cosb, sinb, qh, kth, vtb);
  attn_fused_kernel<<<dim3(512), 256, 0, stream>>>(qh, kth, vtb, yb);
  out_mfma16_kernel<<<dim3(16, 32), 256, 0, stream>>>(yb, Wto, out);
}